// Round 7
// baseline (2896.914 us; speedup 1.0000x reference)
//
#include <hip/hip_runtime.h>

#define ALPHA 0.2f

// ---------------------------------------------------------------------------
// F1: naive GEMM, one thread per (n, c), c = i*64+d in [0,128).
// h[n][i][d] = sum_k x[n][k] * W[i][k][d]; fp32 store into out[n*128+c]
// (H0 plane = out[:,0:64], H1 plane = out[:,64:128]).
// Fused s_r = H·a_src, s_c = H·a_dst (wave == one (n,i); shfl-64 reduce).
// ---------------------------------------------------------------------------
__global__ __launch_bounds__(256) void f7_h(
    const float* __restrict__ x, const float* __restrict__ W,
    const float* __restrict__ a_src, const float* __restrict__ a_dst,
    float* __restrict__ out,
    float* __restrict__ s_r, float* __restrict__ s_c, int N)
{
    long gid = (long)blockIdx.x * 256 + threadIdx.x;
    int n = (int)(gid >> 7);
    int c = (int)(gid & 127);
    if (n >= N) return;                      // wave-uniform exit
    const int i = c >> 6;
    const float* xr = x + (size_t)n * 128;
    const float* wc = W + (size_t)i * 8192 + (c & 63);
    float acc = 0.f;
    #pragma unroll 8
    for (int k = 0; k < 128; ++k)
        acc = fmaf(xr[k], wc[(size_t)k * 64], acc);
    out[(size_t)n * 128 + c] = acc;
    float pr = acc * a_src[c];               // a_src flat idx c == i*64+d
    float pc = acc * a_dst[c];
    #pragma unroll
    for (int off = 32; off; off >>= 1) { pr += __shfl_xor(pr, off); pc += __shfl_xor(pc, off); }
    if ((c & 63) == 0) { s_r[(size_t)i * N + n] = pr; s_c[(size_t)i * N + n] = pc; }
}

// ---------------------------------------------------------------------------
// F2: denom[i][r] += exp(lrelu(s_r[i][row]+s_c[i][col])), both subheads.
// segment_max skipped: |e| <= ~40 -> exp in fp32 range; max subtraction
// cancels exactly in the softmax ratio. rs-renorm skipped (rs == 1 in math;
// fp deviation ~1e-6 relative).
// ---------------------------------------------------------------------------
__global__ __launch_bounds__(256) void f7_edge(
    const int* __restrict__ row, const int* __restrict__ col, int E,
    const float* __restrict__ s_r, const float* __restrict__ s_c,
    float* __restrict__ denom, int N)
{
    int e = blockIdx.x * 256 + threadIdx.x;
    if (e >= E) return;
    int r = row[e], c = col[e];
    if ((unsigned)r >= (unsigned)N || (unsigned)c >= (unsigned)N) return;
    #pragma unroll
    for (int i = 0; i < 2; ++i) {
        float ev = s_r[(size_t)i * N + r] + s_c[(size_t)i * N + c];
        ev = (ev > 0.f) ? ev : ALPHA * ev;
        atomicAdd(denom + (size_t)i * N + r, expf(ev));
    }
}

// ---------------------------------------------------------------------------
// F3: SpMM with on-the-fly attention value. Wave per 8-edge chunk, lane = d.
//   A[r][d] += (exp(lrelu(s_r[r]+s_c[c]))/denom[r]) * Hin[c][hcol+d]
// Hin columns live in d_out (row stride 128). A is N x 64 fp32 in ws.
// s_r/s_c/denom pre-offset per subhead by caller.
// ---------------------------------------------------------------------------
__global__ __launch_bounds__(256) void f7_spmm(
    const int* __restrict__ row, const int* __restrict__ col, int E,
    const float* __restrict__ s_r, const float* __restrict__ s_c,
    const float* __restrict__ denom,
    const float* __restrict__ out, int hcol,
    float* __restrict__ A, int N)
{
    long gid = (long)blockIdx.x * 256 + threadIdx.x;
    long wv  = gid >> 6;
    int  d   = (int)(gid & 63);
    long e0 = wv * 8, e1 = e0 + 8; if (e1 > E) e1 = E;
    for (long e = e0; e < e1; ++e) {
        int r = row[e], c = col[e];
        if ((unsigned)r >= (unsigned)N || (unsigned)c >= (unsigned)N) continue;
        float ev = s_r[r] + s_c[c];
        ev = (ev > 0.f) ? ev : ALPHA * ev;
        float v = expf(ev) / denom[r];
        float h = out[(size_t)c * 128 + hcol + d];
        atomicAdd(A + (size_t)r * 64 + d, v * h);
    }
}

// F4: fp32 plane -> columns [cbase, cbase+64) of d_out (hop1 -> hop2 input).
__global__ __launch_bounds__(256) void f7_copy(
    const float* __restrict__ A, float* __restrict__ out, int cbase, int N)
{
    long gid = (long)blockIdx.x * 256 + threadIdx.x;
    long n = gid >> 6; int d = (int)(gid & 63);
    if (n >= N) return;
    out[(size_t)n * 128 + cbase + d] = A[(size_t)n * 64 + d];
}

// ---------------------------------------------------------------------------
// F5: finalize: NaN guard + bias + NodeAdaptiveEncoder + leaky_relu.
// Wave per (node, subhead), lane = d. Writes out[n*128 + sub*64 + d] (fp32).
// ---------------------------------------------------------------------------
__global__ __launch_bounds__(256) void f7_fin(
    const float* __restrict__ A,
    const float* __restrict__ b, const float* __restrict__ fc,
    const float* __restrict__ bfv,
    float* __restrict__ out, int N, int sub)
{
    long gid = (long)blockIdx.x * 256 + threadIdx.x;
    int n = (int)(gid >> 6), d = (int)(gid & 63);
    if (n >= N) return;
    float vh = A[(size_t)n * 64 + d];
    if (vh != vh) vh = 0.f;                  // val_h[val_h != val_h] = 0
    vh += b[sub * 64 + d];
    float p = vh * fc[sub * 64 + d];         // fc shape (2, 64, 1) -> flat
    #pragma unroll
    for (int off = 32; off; off >>= 1) p += __shfl_xor(p, off);
    float g = 1.f / (1.f + expf(-(p + bfv[sub])));
    float res = fmaxf(vh, 0.f) + g * fminf(vh, 0.f);
    res = (res > 0.f) ? res : ALPHA * res;
    out[(size_t)n * 128 + sub * 64 + d] = res;
}

extern "C" void kernel_launch(void* const* d_in, const int* in_sizes, int n_in,
                              void* d_out, int out_size, void* d_ws, size_t ws_size,
                              hipStream_t stream) {
    // Reference dtypes: float32 everywhere, edge_index int32. Output float32.
    const float* x     = (const float*)d_in[0];
    const int*   ei    = (const int*)d_in[1];
    const float* W     = (const float*)d_in[2];
    const float* b     = (const float*)d_in[3];
    const float* fc    = (const float*)d_in[4];
    const float* bfv   = (const float*)d_in[5];
    const float* a_src = (const float*)d_in[6];
    const float* a_dst = (const float*)d_in[7];
    float* out = (float*)d_out;

    const int N = in_sizes[0] / 128;
    const int E = in_sizes[1] / 2;
    const int* row = ei;
    const int* col = ei + E;

    // ws (28.0 MB): A[N*64 f32] | s_r[2N] | s_c[2N] | denom[2N]
    float* A     = (float*)d_ws;
    float* s_r   = A + (size_t)N * 64;
    float* s_c   = s_r + 2 * (size_t)N;
    float* denom = s_c + 2 * (size_t)N;
    (void)ws_size; (void)n_in; (void)out_size;

    const int hb = (int)(((long)N * 128 + 255) / 256);
    const int eb = (E + 255) / 256;
    const int sb = (int)(((((long)E + 7) / 8) * 64 + 255) / 256);
    const int fb = (int)(((long)N * 64 + 255) / 256);
    const size_t planeB = (size_t)N * 64 * sizeof(float);

    hipMemsetAsync(denom, 0, 2 * (size_t)N * sizeof(float), stream);

    // H planes into d_out: H0 = cols [0,64), H1 = cols [64,128)
    f7_h<<<hb, 256, 0, stream>>>(x, W, a_src, a_dst, out, s_r, s_c, N);
    f7_edge<<<eb, 256, 0, stream>>>(row, col, E, s_r, s_c, denom, N);

    // ---- subhead 0: one hop; then finalize overwrites cols [0,64) ----
    hipMemsetAsync(A, 0, planeB, stream);
    f7_spmm<<<sb, 256, 0, stream>>>(row, col, E, s_r, s_c, denom, out, 0, A, N);
    f7_fin<<<fb, 256, 0, stream>>>(A, b, fc, bfv, out, N, 0);

    // ---- subhead 1: two hops over cols [64,128) ----
    const float* s_r1 = s_r + N; const float* s_c1 = s_c + N; const float* den1 = denom + N;
    hipMemsetAsync(A, 0, planeB, stream);
    f7_spmm<<<sb, 256, 0, stream>>>(row, col, E, s_r1, s_c1, den1, out, 64, A, N);
    f7_copy<<<fb, 256, 0, stream>>>(A, out, 64, N);
    hipMemsetAsync(A, 0, planeB, stream);
    f7_spmm<<<sb, 256, 0, stream>>>(row, col, E, s_r1, s_c1, den1, out, 64, A, N);
    f7_fin<<<fb, 256, 0, stream>>>(A, b, fc, bfv, out, N, 1);
}

// Round 8
// 2134.264 us; speedup vs baseline: 1.3573x; 1.3573x over previous
//
#include <hip/hip_runtime.h>

#define ALPHA 0.2f

// ---------------------------------------------------------------------------
// GEMM: one thread per (n, c), c = i*64+d. h = x@W[i]; fp32 into out[n*128+c]
// (H0 = out[:,0:64], H1 = out[:,64:128]). Fused s_r = H·a_src, s_c = H·a_dst.
// ---------------------------------------------------------------------------
__global__ __launch_bounds__(256) void f7_h(
    const float* __restrict__ x, const float* __restrict__ W,
    const float* __restrict__ a_src, const float* __restrict__ a_dst,
    float* __restrict__ out,
    float* __restrict__ s_r, float* __restrict__ s_c, int N)
{
    long gid = (long)blockIdx.x * 256 + threadIdx.x;
    int n = (int)(gid >> 7);
    int c = (int)(gid & 127);
    if (n >= N) return;
    const int i = c >> 6;
    const float* xr = x + (size_t)n * 128;
    const float* wc = W + (size_t)i * 8192 + (c & 63);
    float acc = 0.f;
    #pragma unroll 8
    for (int k = 0; k < 128; ++k)
        acc = fmaf(xr[k], wc[(size_t)k * 64], acc);
    out[(size_t)n * 128 + c] = acc;
    float pr = acc * a_src[c];
    float pc = acc * a_dst[c];
    #pragma unroll
    for (int off = 32; off; off >>= 1) { pr += __shfl_xor(pr, off); pc += __shfl_xor(pc, off); }
    if ((c & 63) == 0) { s_r[(size_t)i * N + n] = pr; s_c[(size_t)i * N + n] = pc; }
}

// ---------------------------------------------------------------------------
// Edge pass: denom[i][r] += exp(lrelu(...)) for both subheads; row counts.
// segment_max skip exact (cancels in ratio); rs-renorm skip exact (rs==1).
// ---------------------------------------------------------------------------
__global__ __launch_bounds__(256) void f8_edge(
    const int* __restrict__ row, const int* __restrict__ col, int E,
    const float* __restrict__ s_r, const float* __restrict__ s_c,
    float* __restrict__ denom, int* __restrict__ cnt, int N)
{
    int e = blockIdx.x * 256 + threadIdx.x;
    if (e >= E) return;
    int r = row[e], c = col[e];
    if ((unsigned)r >= (unsigned)N || (unsigned)c >= (unsigned)N) return;
    if (cnt) atomicAdd(cnt + r, 1);
    #pragma unroll
    for (int i = 0; i < 2; ++i) {
        float ev = s_r[(size_t)i * N + r] + s_c[(size_t)i * N + c];
        ev = (ev > 0.f) ? ev : ALPHA * ev;
        atomicAdd(denom + (size_t)i * N + r, expf(ev));
    }
}

// --------------------------- 3-phase exclusive scan ------------------------
// phase 1: per-1024-chunk sums
__global__ __launch_bounds__(256) void f8_scan1(
    const int* __restrict__ cnt, int* __restrict__ bsums, int N)
{
    __shared__ int sdat[256];
    int t = threadIdx.x, b = blockIdx.x;
    int s = 0;
    #pragma unroll
    for (int j = 0; j < 4; ++j) {
        int idx = b * 1024 + t * 4 + j;
        if (idx < N) s += cnt[idx];
    }
    sdat[t] = s; __syncthreads();
    for (int o = 1; o < 256; o <<= 1) {
        int add = (t >= o) ? sdat[t - o] : 0;
        __syncthreads();
        sdat[t] += add;
        __syncthreads();
    }
    if (t == 255) bsums[b] = sdat[255];
}
// phase 2: exclusive scan of chunk sums (nb <= 256)
__global__ __launch_bounds__(256) void f8_scan2(
    const int* __restrict__ bsums, int* __restrict__ boffs, int nb)
{
    __shared__ int sdat[256];
    int t = threadIdx.x;
    int v = (t < nb) ? bsums[t] : 0;
    sdat[t] = v; __syncthreads();
    for (int o = 1; o < 256; o <<= 1) {
        int add = (t >= o) ? sdat[t - o] : 0;
        __syncthreads();
        sdat[t] += add;
        __syncthreads();
    }
    if (t < nb) boffs[t] = sdat[t] - v;   // exclusive
}
// phase 3: full exclusive scan -> rp; element N-1 also writes rp[N]
__global__ __launch_bounds__(256) void f8_scan3(
    const int* __restrict__ cnt, const int* __restrict__ boffs,
    int* __restrict__ rp, int N)
{
    __shared__ int sdat[256];
    int t = threadIdx.x, b = blockIdx.x;
    int v[4]; int s = 0;
    #pragma unroll
    for (int j = 0; j < 4; ++j) {
        int idx = b * 1024 + t * 4 + j;
        v[j] = (idx < N) ? cnt[idx] : 0;
        s += v[j];
    }
    sdat[t] = s; __syncthreads();
    for (int o = 1; o < 256; o <<= 1) {
        int add = (t >= o) ? sdat[t - o] : 0;
        __syncthreads();
        sdat[t] += add;
        __syncthreads();
    }
    int excl = boffs[b] + sdat[t] - s;
    #pragma unroll
    for (int j = 0; j < 4; ++j) {
        int idx = b * 1024 + t * 4 + j;
        if (idx < N) {
            rp[idx] = excl;
            if (idx == N - 1) rp[N] = excl + v[j];
            excl += v[j];
        }
    }
}

// scatter: colp bucketed by row (cur = rp copy as cursor)
__global__ __launch_bounds__(256) void f8_scatter(
    const int* __restrict__ row, const int* __restrict__ col, int E,
    int* __restrict__ cur, int* __restrict__ colp, int N)
{
    int e = blockIdx.x * 256 + threadIdx.x;
    if (e >= E) return;
    int r = row[e], c = col[e];
    if ((unsigned)r >= (unsigned)N || (unsigned)c >= (unsigned)N) return;
    int pos = atomicAdd(cur + r, 1);
    colp[pos] = c;
}

// ---------------------------------------------------------------------------
// CSR SpMM (no output atomics): wave per row, lane = d.
//   acc[d] = sum_{pos} (exp(lrelu(s_r[r]+s_c[c]))/denom[r]) * src[c*ss+soff+d]
// ---------------------------------------------------------------------------
__global__ __launch_bounds__(256) void f8_spmm(
    const int* __restrict__ rp, const int* __restrict__ colp,
    const float* __restrict__ s_r, const float* __restrict__ s_c,
    const float* __restrict__ denom,
    const float* __restrict__ src, int ss, int soff,
    float* __restrict__ A, int N)
{
    long gid = (long)blockIdx.x * 256 + threadIdx.x;
    int r = (int)(gid >> 6), d = (int)(gid & 63);
    if (r >= N) return;
    int p0 = rp[r], p1 = rp[r + 1];
    float sr = s_r[r], inv = 1.f / denom[r];
    float acc = 0.f;
    for (int p = p0; p < p1; ++p) {
        int c = colp[p];
        float ev = sr + s_c[c];
        ev = (ev > 0.f) ? ev : ALPHA * ev;
        float v = expf(ev) * inv;
        acc = fmaf(v, src[(size_t)c * ss + soff + d], acc);
    }
    A[(size_t)r * 64 + d] = acc;
}

// Same, with fused NodeAdaptiveEncoder epilogue writing out[r*128+sub*64+d].
__global__ __launch_bounds__(256) void f8_spmm_fin(
    const int* __restrict__ rp, const int* __restrict__ colp,
    const float* __restrict__ s_r, const float* __restrict__ s_c,
    const float* __restrict__ denom,
    const float* __restrict__ src, int ss, int soff,
    const float* __restrict__ b, const float* __restrict__ fc,
    const float* __restrict__ bfv,
    float* __restrict__ out, int N, int sub)
{
    long gid = (long)blockIdx.x * 256 + threadIdx.x;
    int r = (int)(gid >> 6), d = (int)(gid & 63);
    if (r >= N) return;
    int p0 = rp[r], p1 = rp[r + 1];
    float sr = s_r[r], inv = 1.f / denom[r];
    float vh = 0.f;
    for (int p = p0; p < p1; ++p) {
        int c = colp[p];
        float ev = sr + s_c[c];
        ev = (ev > 0.f) ? ev : ALPHA * ev;
        float v = expf(ev) * inv;
        vh = fmaf(v, src[(size_t)c * ss + soff + d], vh);
    }
    if (vh != vh) vh = 0.f;
    vh += b[sub * 64 + d];
    float p = vh * fc[sub * 64 + d];
    #pragma unroll
    for (int off = 32; off; off >>= 1) p += __shfl_xor(p, off);
    float g = 1.f / (1.f + expf(-(p + bfv[sub])));
    float res = fmaxf(vh, 0.f) + g * fminf(vh, 0.f);
    res = (res > 0.f) ? res : ALPHA * res;
    out[(size_t)r * 128 + sub * 64 + d] = res;
}

// standalone finalize (A -> out), for subhead 0 (race-free vs its H plane)
__global__ __launch_bounds__(256) void f8_fin(
    const float* __restrict__ A,
    const float* __restrict__ b, const float* __restrict__ fc,
    const float* __restrict__ bfv,
    float* __restrict__ out, int N, int sub)
{
    long gid = (long)blockIdx.x * 256 + threadIdx.x;
    int n = (int)(gid >> 6), d = (int)(gid & 63);
    if (n >= N) return;
    float vh = A[(size_t)n * 64 + d];
    if (vh != vh) vh = 0.f;
    vh += b[sub * 64 + d];
    float p = vh * fc[sub * 64 + d];
    #pragma unroll
    for (int off = 32; off; off >>= 1) p += __shfl_xor(p, off);
    float g = 1.f / (1.f + expf(-(p + bfv[sub])));
    float res = fmaxf(vh, 0.f) + g * fminf(vh, 0.f);
    res = (res > 0.f) ? res : ALPHA * res;
    out[(size_t)n * 128 + sub * 64 + d] = res;
}

// ------------------- fallback (R7 atomic path) kernels ---------------------
__global__ __launch_bounds__(256) void f7_spmm(
    const int* __restrict__ row, const int* __restrict__ col, int E,
    const float* __restrict__ s_r, const float* __restrict__ s_c,
    const float* __restrict__ denom,
    const float* __restrict__ out, int hcol,
    float* __restrict__ A, int N)
{
    long gid = (long)blockIdx.x * 256 + threadIdx.x;
    long wv  = gid >> 6;
    int  d   = (int)(gid & 63);
    long e0 = wv * 8, e1 = e0 + 8; if (e1 > E) e1 = E;
    for (long e = e0; e < e1; ++e) {
        int r = row[e], c = col[e];
        if ((unsigned)r >= (unsigned)N || (unsigned)c >= (unsigned)N) continue;
        float ev = s_r[r] + s_c[c];
        ev = (ev > 0.f) ? ev : ALPHA * ev;
        float v = expf(ev) / denom[r];
        atomicAdd(A + (size_t)r * 64 + d, v * out[(size_t)c * 128 + hcol + d]);
    }
}
__global__ __launch_bounds__(256) void f7_copy(
    const float* __restrict__ A, float* __restrict__ out, int cbase, int N)
{
    long gid = (long)blockIdx.x * 256 + threadIdx.x;
    long n = gid >> 6; int d = (int)(gid & 63);
    if (n >= N) return;
    out[(size_t)n * 128 + cbase + d] = A[(size_t)n * 64 + d];
}

extern "C" void kernel_launch(void* const* d_in, const int* in_sizes, int n_in,
                              void* d_out, int out_size, void* d_ws, size_t ws_size,
                              hipStream_t stream) {
    const float* x     = (const float*)d_in[0];
    const int*   ei    = (const int*)d_in[1];
    const float* W     = (const float*)d_in[2];
    const float* b     = (const float*)d_in[3];
    const float* fc    = (const float*)d_in[4];
    const float* bfv   = (const float*)d_in[5];
    const float* a_src = (const float*)d_in[6];
    const float* a_dst = (const float*)d_in[7];
    float* out = (float*)d_out;

    const int N = in_sizes[0] / 128;
    const int E = in_sizes[1] / 2;
    const int* row = ei;
    const int* col = ei + E;

    // ws layout (CSR path, ~42 MB):
    // A[N*64] f32 | s_r[2N] | s_c[2N] | denom[2N] | rp[N+1] | cnt[N] |
    // bsums[256] | boffs[256] | colp[E]
    float* A     = (float*)d_ws;
    float* s_r   = A + (size_t)N * 64;
    float* s_c   = s_r + 2 * (size_t)N;
    float* denom = s_c + 2 * (size_t)N;
    int*   rp    = (int*)(denom + 2 * (size_t)N);
    int*   cnt   = rp + (N + 1);
    int*   bsums = cnt + N;
    int*   boffs = bsums + 256;
    int*   colp  = boffs + 256;
    size_t need  = (size_t)((char*)(colp + E) - (char*)d_ws);
    const bool csr = (ws_size >= need);
    (void)n_in; (void)out_size;

    const int hb = (int)(((long)N * 128 + 255) / 256);
    const int eb = (E + 255) / 256;
    const int rb = (int)(((long)N * 64 + 255) / 256);   // wave-per-row grids
    const int nb = (N + 1023) / 1024;
    const size_t planeB = (size_t)N * 64 * sizeof(float);

    hipMemsetAsync(denom, 0, 2 * (size_t)N * sizeof(float), stream);
    if (csr) hipMemsetAsync(cnt, 0, (size_t)N * sizeof(int), stream);

    f7_h<<<hb, 256, 0, stream>>>(x, W, a_src, a_dst, out, s_r, s_c, N);
    f8_edge<<<eb, 256, 0, stream>>>(row, col, E, s_r, s_c, denom, csr ? cnt : nullptr, N);

    const float* s_r1 = s_r + N; const float* s_c1 = s_c + N; const float* den1 = denom + N;

    if (csr) {
        f8_scan1<<<nb, 256, 0, stream>>>(cnt, bsums, N);
        f8_scan2<<<1, 256, 0, stream>>>(bsums, boffs, nb);
        f8_scan3<<<nb, 256, 0, stream>>>(cnt, boffs, rp, N);
        hipMemcpyAsync(cnt, rp, (size_t)N * sizeof(int), hipMemcpyDeviceToDevice, stream);
        f8_scatter<<<eb, 256, 0, stream>>>(row, col, E, cnt, colp, N);

        // subhead 0: 1 hop from H0 (out cols 0-63) -> A, then finalize
        f8_spmm<<<rb, 256, 0, stream>>>(rp, colp, s_r, s_c, denom, out, 128, 0, A, N);
        f8_fin<<<rb, 256, 0, stream>>>(A, b, fc, bfv, out, N, 0);
        // subhead 1: hop1 from H1 (out cols 64-127) -> A; hop2 from A -> out (fused fin)
        f8_spmm<<<rb, 256, 0, stream>>>(rp, colp, s_r1, s_c1, den1, out, 128, 64, A, N);
        f8_spmm_fin<<<rb, 256, 0, stream>>>(rp, colp, s_r1, s_c1, den1, A, 64, 0,
                                            b, fc, bfv, out, N, 1);
    } else {
        // proven R7 atomic path (28 MB ws)
        const int sb = (int)(((((long)E + 7) / 8) * 64 + 255) / 256);
        hipMemsetAsync(A, 0, planeB, stream);
        f7_spmm<<<sb, 256, 0, stream>>>(row, col, E, s_r, s_c, denom, out, 0, A, N);
        f8_fin<<<rb, 256, 0, stream>>>(A, b, fc, bfv, out, N, 0);
        hipMemsetAsync(A, 0, planeB, stream);
        f7_spmm<<<sb, 256, 0, stream>>>(row, col, E, s_r1, s_c1, den1, out, 64, A, N);
        f7_copy<<<rb, 256, 0, stream>>>(A, out, 64, N);
        hipMemsetAsync(A, 0, planeB, stream);
        f7_spmm<<<sb, 256, 0, stream>>>(row, col, E, s_r1, s_c1, den1, out, 64, A, N);
        f8_fin<<<rb, 256, 0, stream>>>(A, b, fc, bfv, out, N, 1);
    }
}